// Round 1
// baseline (215.378 us; speedup 1.0000x reference)
//
#include <hip/hip_runtime.h>

#define NB 16
#define SQ 2048
#define SK 2048
#define DH 64
#define TK 32

typedef __attribute__((ext_vector_type(8))) short short8;
typedef __attribute__((ext_vector_type(8))) __bf16 bf16x8;
typedef __attribute__((ext_vector_type(4))) float floatx4;

#define RSK 72   // ks row stride in halfwords (144 B, 16B-aligned)
#define RSV 36   // vt row stride in words    (144 B)
#define RSP 36   // pb row stride in words    (144 B)

__device__ __forceinline__ short f2bf_s(float f) {
  union { float f; unsigned u; } v; v.f = f;
  unsigned r = (v.u + 0x7FFFu + ((v.u >> 16) & 1u)) >> 16;  // RNE
  return (short)(unsigned short)r;
}

__device__ __forceinline__ short8 pack8(const float* x) {
  short8 s;
#pragma unroll
  for (int i = 0; i < 8; ++i) s[i] = f2bf_s(x[i]);
  return s;
}

__device__ __forceinline__ floatx4 mfma16(short8 a, short8 b, floatx4 c) {
  return __builtin_amdgcn_mfma_f32_16x16x32_bf16(
      __builtin_bit_cast(bf16x8, a), __builtin_bit_cast(bf16x8, b), c, 0, 0, 0);
}

__global__ __launch_bounds__(256)
void attn_flash_bf16(const float* __restrict__ Q, const float* __restrict__ K,
                     const float* __restrict__ V, const int* __restrict__ mask,
                     float* __restrict__ Out) {
  __shared__ __align__(16) short ks[TK * RSK];      // K tile, bf16 [32][64]+pad
  __shared__ __align__(16) float vt[DH * RSV];      // V tile transposed fp32 [64][32]+pad
  __shared__ __align__(16) float pb[4 * 16 * RSP];  // per-wave P [16][32]+pad
  __shared__ float mb[TK];                          // mask bias

  const int b    = blockIdx.x >> 5;   // 32 q-tiles per batch
  const int qt   = blockIdx.x & 31;
  const int tid  = threadIdx.x;
  const int wave = tid >> 6;
  const int lane = tid & 63;
  const int L    = lane & 15;
  const int quad = lane >> 4;
  const int q0w  = qt * 64 + wave * 16;

  const float* Qb = Q + (size_t)b * SQ * DH;
  const float* Kb = K + (size_t)b * SK * DH;
  const float* Vb = V + (size_t)b * SK * DH;
  const int*  mkb = mask + b * SK;

  // ---- Q A-fragments (rows q0w+L, scale 1/8 folded in exactly) ----
  short8 qf[2];
  {
    const float* qp = Qb + (size_t)(q0w + L) * DH + 8 * quad;
#pragma unroll
    for (int c = 0; c < 2; ++c) {
      floatx4 a  = *(const floatx4*)(qp + 32 * c);
      floatx4 b2 = *(const floatx4*)(qp + 32 * c + 4);
      float t8[8];
#pragma unroll
      for (int j = 0; j < 4; ++j) { t8[j] = a[j] * 0.125f; t8[4 + j] = b2[j] * 0.125f; }
      qf[c] = pack8(t8);
    }
  }

  floatx4 o[4];
  float m_r[4], l_r[4];
#pragma unroll
  for (int n = 0; n < 4; ++n) { o[n] = (floatx4){0.f, 0.f, 0.f, 0.f}; }
#pragma unroll
  for (int r = 0; r < 4; ++r) { m_r[r] = -1e30f; l_r[r] = 0.f; }

  float* pbw = pb + wave * 16 * RSP;

  for (int k0 = 0; k0 < SK; k0 += TK) {
    // ---- cooperative staging: K (bf16), V (fp32 transposed), mask bias ----
    {
      const int key = tid >> 3;        // 0..31
      const int d8  = (tid & 7) * 8;   // 0..56
      const float* kp = Kb + (size_t)(k0 + key) * DH + d8;
      floatx4 ka = *(const floatx4*)kp;
      floatx4 kb2 = *(const floatx4*)(kp + 4);
      float t8[8];
#pragma unroll
      for (int j = 0; j < 4; ++j) { t8[j] = ka[j]; t8[4 + j] = kb2[j]; }
      *(short8*)(ks + key * RSK + d8) = pack8(t8);

      const float* vp = Vb + (size_t)(k0 + key) * DH + d8;
      floatx4 va = *(const floatx4*)vp;
      floatx4 vb2 = *(const floatx4*)(vp + 4);
#pragma unroll
      for (int j = 0; j < 4; ++j) {
        vt[(d8 + j) * RSV + key]     = va[j];
        vt[(d8 + 4 + j) * RSV + key] = vb2[j];
      }
      if (tid < TK) mb[tid] = mkb[k0 + tid] ? -1e30f : 0.0f;
    }
    __syncthreads();

    // ---- S = Q K^T for two 16-key tiles ----
    short8 kf0c0 = *(short8*)(ks + (0  + L) * RSK + 8 * quad);
    short8 kf0c1 = *(short8*)(ks + (0  + L) * RSK + 32 + 8 * quad);
    short8 kf1c0 = *(short8*)(ks + (16 + L) * RSK + 8 * quad);
    short8 kf1c1 = *(short8*)(ks + (16 + L) * RSK + 32 + 8 * quad);

    floatx4 zero = (floatx4){0.f, 0.f, 0.f, 0.f};
    floatx4 s0 = mfma16(qf[0], kf0c0, zero); s0 = mfma16(qf[1], kf0c1, s0);
    floatx4 s1 = mfma16(qf[0], kf1c0, zero); s1 = mfma16(qf[1], kf1c1, s1);

    const float mb0 = mb[L], mb1 = mb[16 + L];

    // ---- online softmax (per row r; row = quad*4+r, cols live in 16-lane quad) ----
    float p0[4], p1[4], alpha[4];
#pragma unroll
    for (int r = 0; r < 4; ++r) {
      float a0 = s0[r] + mb0, a1 = s1[r] + mb1;
      float rm = fmaxf(a0, a1);
      rm = fmaxf(rm, __shfl_xor(rm, 1));
      rm = fmaxf(rm, __shfl_xor(rm, 2));
      rm = fmaxf(rm, __shfl_xor(rm, 4));
      rm = fmaxf(rm, __shfl_xor(rm, 8));
      float mn = fmaxf(m_r[r], rm);
      float al = __expf(m_r[r] - mn);
      m_r[r] = mn;
      alpha[r] = al;
      p0[r] = __expf(a0 - mn);
      p1[r] = __expf(a1 - mn);
      float rs = p0[r] + p1[r];
      rs += __shfl_xor(rs, 1);
      rs += __shfl_xor(rs, 2);
      rs += __shfl_xor(rs, 4);
      rs += __shfl_xor(rs, 8);
      l_r[r] = al * l_r[r] + rs;
    }
#pragma unroll
    for (int n = 0; n < 4; ++n)
#pragma unroll
      for (int r = 0; r < 4; ++r) o[n][r] *= alpha[r];

    // ---- P: C-layout -> LDS -> A-layout (m120 pattern) ----
#pragma unroll
    for (int r = 0; r < 4; ++r) {
      pbw[(quad * 4 + r) * RSP + L]      = p0[r];
      pbw[(quad * 4 + r) * RSP + 16 + L] = p1[r];
    }
    floatx4 pa  = *(floatx4*)(pbw + L * RSP + 8 * quad);
    floatx4 pa2 = *(floatx4*)(pbw + L * RSP + 8 * quad + 4);
    float pt[8];
#pragma unroll
    for (int j = 0; j < 4; ++j) { pt[j] = pa[j]; pt[4 + j] = pa2[j]; }
    short8 pf = pack8(pt);

    // ---- O += P V ----
#pragma unroll
    for (int n = 0; n < 4; ++n) {
      floatx4 va  = *(floatx4*)(vt + (16 * n + L) * RSV + 8 * quad);
      floatx4 va2 = *(floatx4*)(vt + (16 * n + L) * RSV + 8 * quad + 4);
      float t8[8];
#pragma unroll
      for (int j = 0; j < 4; ++j) { t8[j] = va[j]; t8[4 + j] = va2[j]; }
      short8 vf = pack8(t8);
      o[n] = mfma16(pf, vf, o[n]);
    }
    __syncthreads();
  }

  // ---- epilogue: normalize and store (C-layout rows) ----
#pragma unroll
  for (int r = 0; r < 4; ++r) {
    float inv = 1.0f / l_r[r];
    size_t row = (size_t)b * SQ + q0w + quad * 4 + r;
#pragma unroll
    for (int n = 0; n < 4; ++n)
      Out[row * DH + 16 * n + L] = o[n][r] * inv;
  }
}

extern "C" void kernel_launch(void* const* d_in, const int* in_sizes, int n_in,
                              void* d_out, int out_size, void* d_ws, size_t ws_size,
                              hipStream_t stream) {
  const float* Q = (const float*)d_in[0];
  const float* K = (const float*)d_in[1];
  const float* V = (const float*)d_in[2];
  const int* mask = (const int*)d_in[3];
  float* Out = (float*)d_out;
  dim3 grid(NB * (SQ / 64));   // 512 blocks: 64 q-rows each
  dim3 block(256);             // 4 waves x 16 q-rows
  attn_flash_bf16<<<grid, block, 0, stream>>>(Q, K, V, mask, Out);
}

// Round 3
// 166.593 us; speedup vs baseline: 1.2928x; 1.2928x over previous
//
#include <hip/hip_runtime.h>

#define NB 16
#define SQ 2048
#define SK 2048
#define DH 64
#define TK 64
#define RS 72   // LDS row stride in halfwords (144 B, keeps 16B alignment)

typedef __attribute__((ext_vector_type(8))) short short8;
typedef __attribute__((ext_vector_type(8))) __bf16 bf16x8;
typedef __attribute__((ext_vector_type(4))) float floatx4;

__device__ __forceinline__ unsigned f2bf_u(float f) {
  union { float f; unsigned u; } v; v.f = f;
  return (v.u + 0x7FFFu + ((v.u >> 16) & 1u)) >> 16;  // RNE
}
__device__ __forceinline__ unsigned pk2(float a, float b) {
  return f2bf_u(a) | (f2bf_u(b) << 16);
}
__device__ __forceinline__ short bf1(float a) {
  return (short)(unsigned short)f2bf_u(a);
}
__device__ __forceinline__ floatx4 mfma16(short8 a, short8 b, floatx4 c) {
  return __builtin_amdgcn_mfma_f32_16x16x32_bf16(
      __builtin_bit_cast(bf16x8, a), __builtin_bit_cast(bf16x8, b), c, 0, 0, 0);
}

__global__ __launch_bounds__(256)
void attn_flash_bf16(const float* __restrict__ Q, const float* __restrict__ K,
                     const float* __restrict__ V, const int* __restrict__ mask,
                     float* __restrict__ Out) {
  __shared__ __align__(16) short ks[TK * RS];      // K tile bf16 [64 keys][64 d + pad]
  __shared__ __align__(16) short vt[DH * RS];      // V^T tile bf16 [64 d][64 keys + pad]
  __shared__ __align__(16) short pb[4 * 16 * RS];  // per-wave P bf16 [16][64 + pad]
  __shared__ float mb[TK];                         // mask bias

  const int b    = blockIdx.x >> 5;
  const int qt   = blockIdx.x & 31;
  const int tid  = threadIdx.x;
  const int wave = tid >> 6;
  const int lane = tid & 63;
  const int L    = lane & 15;
  const int quad = lane >> 4;
  const int q0w  = qt * 64 + wave * 16;

  const float* Qb = Q + (size_t)b * SQ * DH;
  const float* Kb = K + (size_t)b * SK * DH;
  const float* Vb = V + (size_t)b * SK * DH;
  const int*  mkb = mask + b * SK;

  // ---- Q A-fragments (rows q0w+L), scale 1/8 folded in exactly ----
  short8 qf[2];
  {
    const float* qp = Qb + (size_t)(q0w + L) * DH + 8 * quad;
#pragma unroll
    for (int c = 0; c < 2; ++c) {
      floatx4 a  = *(const floatx4*)(qp + 32 * c);
      floatx4 a2 = *(const floatx4*)(qp + 32 * c + 4);
      union { unsigned u[4]; short8 s; } w;
      w.u[0] = pk2(a[0] * 0.125f, a[1] * 0.125f);
      w.u[1] = pk2(a[2] * 0.125f, a[3] * 0.125f);
      w.u[2] = pk2(a2[0] * 0.125f, a2[1] * 0.125f);
      w.u[3] = pk2(a2[2] * 0.125f, a2[3] * 0.125f);
      qf[c] = w.s;
    }
  }

  floatx4 o[4];
  float m_r[4], l_r[4];
#pragma unroll
  for (int n = 0; n < 4; ++n) o[n] = (floatx4){0.f, 0.f, 0.f, 0.f};
#pragma unroll
  for (int r = 0; r < 4; ++r) { m_r[r] = -1e30f; l_r[r] = 0.f; }

  short* pbw = pb + wave * 16 * RS;

  // staging index precompute
  const int kkey = tid >> 2;          // 0..63
  const int kds  = (tid & 3) * 16;    // 0,16,32,48
  const int vc   = tid & 31;          // key-pair 0..31 -> keys 2c,2c+1
  const int vdg  = (tid >> 5) * 8;    // d group 0,8,...,56

  for (int k0 = 0; k0 < SK; k0 += TK) {
    // ---- cooperative staging: K bf16 rows, V bf16 transposed, mask bias ----
    {
      const float* kp = Kb + (size_t)(k0 + kkey) * DH + kds;
      floatx4 c0 = *(const floatx4*)(kp);
      floatx4 c1 = *(const floatx4*)(kp + 4);
      floatx4 c2 = *(const floatx4*)(kp + 8);
      floatx4 c3 = *(const floatx4*)(kp + 12);
      union { unsigned u[4]; short8 s; } w0, w1;
      w0.u[0] = pk2(c0[0], c0[1]); w0.u[1] = pk2(c0[2], c0[3]);
      w0.u[2] = pk2(c1[0], c1[1]); w0.u[3] = pk2(c1[2], c1[3]);
      w1.u[0] = pk2(c2[0], c2[1]); w1.u[1] = pk2(c2[2], c2[3]);
      w1.u[2] = pk2(c3[0], c3[1]); w1.u[3] = pk2(c3[2], c3[3]);
      *(short8*)(ks + kkey * RS + kds)     = w0.s;
      *(short8*)(ks + kkey * RS + kds + 8) = w1.s;

      const float* vp0 = Vb + (size_t)(k0 + 2 * vc) * DH + vdg;
      const float* vp1 = vp0 + DH;
      floatx4 va  = *(const floatx4*)(vp0);
      floatx4 va2 = *(const floatx4*)(vp0 + 4);
      floatx4 vb  = *(const floatx4*)(vp1);
      floatx4 vb2 = *(const floatx4*)(vp1 + 4);
      unsigned* vtw = (unsigned*)vt;  // vt halfword addr (d*RS + 2c) is even -> word d*36+c
#pragma unroll
      for (int j = 0; j < 4; ++j) {
        vtw[(vdg + j) * 36 + vc]     = pk2(va[j],  vb[j]);
        vtw[(vdg + 4 + j) * 36 + vc] = pk2(va2[j], vb2[j]);
      }
      if (tid < TK) mb[tid] = mkb[k0 + tid] ? -1e30f : 0.0f;
    }
    __syncthreads();

    // ---- S = Q K^T : 4 key-subtiles of 16, k-dim 64 = 2 MFMAs each ----
    floatx4 s[4];
#pragma unroll
    for (int t = 0; t < 4; ++t) {
      short8 kf0 = *(short8*)(ks + (16 * t + L) * RS + quad * 8);
      short8 kf1 = *(short8*)(ks + (16 * t + L) * RS + 32 + quad * 8);
      floatx4 z = (floatx4){0.f, 0.f, 0.f, 0.f};
      s[t] = mfma16(qf[0], kf0, z);
      s[t] = mfma16(qf[1], kf1, s[t]);
    }

    const float mbv0 = mb[L], mbv1 = mb[16 + L], mbv2 = mb[32 + L], mbv3 = mb[48 + L];

    // ---- online softmax per row (row = quad*4+r, cols 16t+L) ----
    float alpha[4];
#pragma unroll
    for (int r = 0; r < 4; ++r) {
      float a0 = s[0][r] + mbv0, a1 = s[1][r] + mbv1;
      float a2 = s[2][r] + mbv2, a3 = s[3][r] + mbv3;
      float rm = fmaxf(fmaxf(a0, a1), fmaxf(a2, a3));
      rm = fmaxf(rm, __shfl_xor(rm, 1));
      rm = fmaxf(rm, __shfl_xor(rm, 2));
      rm = fmaxf(rm, __shfl_xor(rm, 4));
      rm = fmaxf(rm, __shfl_xor(rm, 8));
      float mn = fmaxf(m_r[r], rm);
      float al = __expf(m_r[r] - mn);
      m_r[r] = mn;
      alpha[r] = al;
      float p0 = __expf(a0 - mn), p1 = __expf(a1 - mn);
      float p2 = __expf(a2 - mn), p3 = __expf(a3 - mn);
      short* pr = pbw + (quad * 4 + r) * RS + L;
      pr[0]  = bf1(p0);
      pr[16] = bf1(p1);
      pr[32] = bf1(p2);
      pr[48] = bf1(p3);
      float rs = (p0 + p1) + (p2 + p3);
      rs += __shfl_xor(rs, 1);
      rs += __shfl_xor(rs, 2);
      rs += __shfl_xor(rs, 4);
      rs += __shfl_xor(rs, 8);
      l_r[r] = al * l_r[r] + rs;
    }
#pragma unroll
    for (int n = 0; n < 4; ++n)
#pragma unroll
      for (int r = 0; r < 4; ++r) o[n][r] *= alpha[r];

    // ---- P fragments (bf16, direct from LDS) ----
    short8 pf0 = *(short8*)(pbw + L * RS + quad * 8);
    short8 pf1 = *(short8*)(pbw + L * RS + 32 + quad * 8);

    // ---- O += P V ----
#pragma unroll
    for (int n = 0; n < 4; ++n) {
      short8 vf0 = *(short8*)(vt + (16 * n + L) * RS + quad * 8);
      short8 vf1 = *(short8*)(vt + (16 * n + L) * RS + 32 + quad * 8);
      o[n] = mfma16(pf0, vf0, o[n]);
      o[n] = mfma16(pf1, vf1, o[n]);
    }
    __syncthreads();
  }

  // ---- epilogue: normalize and store ----
#pragma unroll
  for (int r = 0; r < 4; ++r) {
    float inv = 1.0f / l_r[r];
    size_t row = (size_t)b * SQ + q0w + quad * 4 + r;
#pragma unroll
    for (int n = 0; n < 4; ++n)
      Out[row * DH + 16 * n + L] = o[n][r] * inv;
  }
}

extern "C" void kernel_launch(void* const* d_in, const int* in_sizes, int n_in,
                              void* d_out, int out_size, void* d_ws, size_t ws_size,
                              hipStream_t stream) {
  const float* Q = (const float*)d_in[0];
  const float* K = (const float*)d_in[1];
  const float* V = (const float*)d_in[2];
  const int* mask = (const int*)d_in[3];
  float* Out = (float*)d_out;
  dim3 grid(NB * (SQ / 64));
  dim3 block(256);
  attn_flash_bf16<<<grid, block, 0, stream>>>(Q, K, V, mask, Out);
}

// Round 4
// 141.199 us; speedup vs baseline: 1.5254x; 1.1798x over previous
//
#include <hip/hip_runtime.h>
#include <hip/hip_bf16.h>

#define NB 16
#define SQ 2048
#define SK 2048
#define DH 64
#define RS 72          // LDS row stride in halfwords (144 B)
#define NKT (SK / 64)  // 32 key tiles of 64

typedef __attribute__((ext_vector_type(8))) short short8;
typedef __attribute__((ext_vector_type(8))) __bf16 bf16x8;
typedef __attribute__((ext_vector_type(4))) float floatx4;

__device__ __forceinline__ unsigned pk2(float a, float b) {
  __hip_bfloat162 h = __float22bfloat162_rn(make_float2(a, b));
  unsigned u; __builtin_memcpy(&u, &h, 4); return u;
}
__device__ __forceinline__ short bf1(float a) {
  __hip_bfloat16 h = __float2bfloat16(a);
  short s; __builtin_memcpy(&s, &h, 2); return s;
}
__device__ __forceinline__ floatx4 mfma16(short8 a, short8 b, floatx4 c) {
  return __builtin_amdgcn_mfma_f32_16x16x32_bf16(
      __builtin_bit_cast(bf16x8, a), __builtin_bit_cast(bf16x8, b), c, 0, 0, 0);
}

// ---------- prepass: K fp32 -> bf16 row-major ----------
__global__ __launch_bounds__(256)
void conv_k(const float* __restrict__ K, short* __restrict__ Kb) {
  size_t i8 = ((size_t)blockIdx.x * 256 + threadIdx.x) * 8;
  floatx4 a = *(const floatx4*)(K + i8);
  floatx4 b = *(const floatx4*)(K + i8 + 4);
  union { unsigned u[4]; short8 s; } w;
  w.u[0] = pk2(a[0], a[1]); w.u[1] = pk2(a[2], a[3]);
  w.u[2] = pk2(b[0], b[1]); w.u[3] = pk2(b[2], b[3]);
  *(short8*)(Kb + i8) = w.s;
}

// ---------- prepass: V fp32 -> bf16 transposed, tile-packed ----------
// Output: per (b,kt) tile of 4096 shorts laid out [d=0..63][key=0..63].
__global__ __launch_bounds__(256)
void conv_vt(const float* __restrict__ V, short* __restrict__ Vt) {
  __shared__ short tl[64 * 64];
  const int t = threadIdx.x;
  const int bt = blockIdx.x;             // b*32 + kt
  const int key = t >> 2, d0 = (t & 3) * 16;
  const float* src = V + ((size_t)bt * 64 + key) * 64 + d0;
#pragma unroll
  for (int c = 0; c < 4; ++c) {
    floatx4 v = *(const floatx4*)(src + 4 * c);
#pragma unroll
    for (int j = 0; j < 4; ++j) tl[(d0 + 4 * c + j) * 64 + key] = bf1(v[j]);
  }
  __syncthreads();
  short* dst = Vt + (size_t)bt * 4096;
#pragma unroll
  for (int i = 0; i < 2; ++i) {
    int idx = i * 2048 + t * 8;
    *(short8*)(dst + idx) = *(const short8*)(tl + idx);
  }
}

// ---------- prepass: mask -> float bias ----------
__global__ __launch_bounds__(256)
void conv_bias(const int* __restrict__ m, float* __restrict__ bias) {
  int i = blockIdx.x * 256 + threadIdx.x;
  bias[i] = m[i] ? -1e30f : 0.0f;
}

// ---------- main flash-attention kernel ----------
__global__ __launch_bounds__(256)
void attn_main(const float* __restrict__ Q, const short* __restrict__ Kb,
               const short* __restrict__ Vt, const float* __restrict__ bias,
               float* __restrict__ Out) {
  __shared__ __align__(16) short ks[64 * RS];      // K tile bf16 [64 keys][64 d + pad]
  __shared__ __align__(16) short vt[64 * RS];      // V^T tile bf16 [64 d][64 keys + pad]
  __shared__ __align__(16) short pb[4 * 16 * RS];  // per-wave P bf16

  const int b    = blockIdx.x >> 5;
  const int qt   = blockIdx.x & 31;
  const int tid  = threadIdx.x;
  const int wave = tid >> 6;
  const int lane = tid & 63;
  const int L    = lane & 15;
  const int quad = lane >> 4;
  const int q0w  = qt * 64 + wave * 16;

  // ---- Q fragments, scale (1/8)*log2(e) folded in (base-2 softmax) ----
  const float QS = 0.125f * 1.4426950408889634f;
  short8 qf[2];
  {
    const float* qp = Q + ((size_t)b * SQ + q0w + L) * DH + 8 * quad;
#pragma unroll
    for (int c = 0; c < 2; ++c) {
      floatx4 a  = *(const floatx4*)(qp + 32 * c);
      floatx4 a2 = *(const floatx4*)(qp + 32 * c + 4);
      union { unsigned u[4]; short8 s; } w;
      w.u[0] = pk2(a[0] * QS, a[1] * QS);
      w.u[1] = pk2(a[2] * QS, a[3] * QS);
      w.u[2] = pk2(a2[0] * QS, a2[1] * QS);
      w.u[3] = pk2(a2[2] * QS, a2[3] * QS);
      qf[c] = w.s;
    }
  }

  floatx4 o[4];
  float m_r[4], l_r[4];
#pragma unroll
  for (int n = 0; n < 4; ++n) o[n] = (floatx4){0.f, 0.f, 0.f, 0.f};
#pragma unroll
  for (int r = 0; r < 4; ++r) { m_r[r] = -1e30f; l_r[r] = 0.f; }

  short* pbw = pb + wave * 16 * RS;

  const short* kg = Kb + (size_t)b * SK * DH;   // batch base (tile kt at +kt*4096)
  const short* vg = Vt + (size_t)b * 32 * 4096;
  const float* bg = bias + b * SK;

  const int srow = tid >> 3;         // 0..31
  const int scol = (tid & 7) * 8;

  // prefetch tile 0 into registers
  short8 kr[2], vr[2];
#pragma unroll
  for (int i = 0; i < 2; ++i) {
    kr[i] = *(const short8*)(kg + i * 2048 + tid * 8);
    vr[i] = *(const short8*)(vg + i * 2048 + tid * 8);
  }

  for (int kt = 0; kt < NKT; ++kt) {
    // ---- stage current tile from regs ----
#pragma unroll
    for (int i = 0; i < 2; ++i) {
      int row = i * 32 + srow;
      *(short8*)(ks + row * RS + scol) = kr[i];
      *(short8*)(vt + row * RS + scol) = vr[i];
    }
    __syncthreads();

    // ---- issue next tile's loads (latency hidden under compute) ----
    if (kt + 1 < NKT) {
      const short* kn = kg + (size_t)(kt + 1) * 4096;
      const short* vn = vg + (size_t)(kt + 1) * 4096;
#pragma unroll
      for (int i = 0; i < 2; ++i) {
        kr[i] = *(const short8*)(kn + i * 2048 + tid * 8);
        vr[i] = *(const short8*)(vn + i * 2048 + tid * 8);
      }
    }

    // ---- S = Q K^T ----
    floatx4 s[4];
#pragma unroll
    for (int t = 0; t < 4; ++t) {
      short8 kf0 = *(short8*)(ks + (16 * t + L) * RS + quad * 8);
      short8 kf1 = *(short8*)(ks + (16 * t + L) * RS + 32 + quad * 8);
      floatx4 z = (floatx4){0.f, 0.f, 0.f, 0.f};
      s[t] = mfma16(qf[0], kf0, z);
      s[t] = mfma16(qf[1], kf1, s[t]);
    }

    const int kb0 = kt * 64;
    const float mbv0 = bg[kb0 + L],      mbv1 = bg[kb0 + 16 + L];
    const float mbv2 = bg[kb0 + 32 + L], mbv3 = bg[kb0 + 48 + L];

    // ---- online softmax (base 2) ----
    float alpha[4];
#pragma unroll
    for (int r = 0; r < 4; ++r) {
      float a0 = s[0][r] + mbv0, a1 = s[1][r] + mbv1;
      float a2 = s[2][r] + mbv2, a3 = s[3][r] + mbv3;
      float rm = fmaxf(fmaxf(a0, a1), fmaxf(a2, a3));
      rm = fmaxf(rm, __shfl_xor(rm, 1));
      rm = fmaxf(rm, __shfl_xor(rm, 2));
      rm = fmaxf(rm, __shfl_xor(rm, 4));
      rm = fmaxf(rm, __shfl_xor(rm, 8));
      float mn = fmaxf(m_r[r], rm);
      float al = __builtin_amdgcn_exp2f(m_r[r] - mn);
      m_r[r] = mn;
      alpha[r] = al;
      float p0 = __builtin_amdgcn_exp2f(a0 - mn);
      float p1 = __builtin_amdgcn_exp2f(a1 - mn);
      float p2 = __builtin_amdgcn_exp2f(a2 - mn);
      float p3 = __builtin_amdgcn_exp2f(a3 - mn);
      short* pr = pbw + (quad * 4 + r) * RS + L;
      pr[0]  = bf1(p0);
      pr[16] = bf1(p1);
      pr[32] = bf1(p2);
      pr[48] = bf1(p3);
      float rs = (p0 + p1) + (p2 + p3);
      rs += __shfl_xor(rs, 1);
      rs += __shfl_xor(rs, 2);
      rs += __shfl_xor(rs, 4);
      rs += __shfl_xor(rs, 8);
      l_r[r] = al * l_r[r] + rs;
    }
#pragma unroll
    for (int n = 0; n < 4; ++n)
#pragma unroll
      for (int r = 0; r < 4; ++r) o[n][r] *= alpha[r];

    // ---- P fragments ----
    short8 pf0 = *(short8*)(pbw + L * RS + quad * 8);
    short8 pf1 = *(short8*)(pbw + L * RS + 32 + quad * 8);

    // ---- O += P V ----
#pragma unroll
    for (int n = 0; n < 4; ++n) {
      short8 vf0 = *(short8*)(vt + (16 * n + L) * RS + quad * 8);
      short8 vf1 = *(short8*)(vt + (16 * n + L) * RS + 32 + quad * 8);
      o[n] = mfma16(pf0, vf0, o[n]);
      o[n] = mfma16(pf1, vf1, o[n]);
    }
    __syncthreads();
  }

  // ---- epilogue ----
#pragma unroll
  for (int r = 0; r < 4; ++r) {
    float inv = 1.0f / l_r[r];
    size_t row = (size_t)b * SQ + q0w + quad * 4 + r;
#pragma unroll
    for (int n = 0; n < 4; ++n)
      Out[row * DH + 16 * n + L] = o[n][r] * inv;
  }
}

extern "C" void kernel_launch(void* const* d_in, const int* in_sizes, int n_in,
                              void* d_out, int out_size, void* d_ws, size_t ws_size,
                              hipStream_t stream) {
  const float* Q = (const float*)d_in[0];
  const float* K = (const float*)d_in[1];
  const float* V = (const float*)d_in[2];
  const int* mask = (const int*)d_in[3];
  float* Out = (float*)d_out;

  short* Kb   = (short*)d_ws;
  short* Vt   = (short*)((char*)d_ws + (size_t)NB * SK * DH * 2);
  float* bias = (float*)((char*)d_ws + (size_t)NB * SK * DH * 4);

  conv_k   <<<NB * SK * DH / (256 * 8), 256, 0, stream>>>(K, Kb);
  conv_vt  <<<NB * NKT, 256, 0, stream>>>(V, Vt);
  conv_bias<<<NB * SK / 256, 256, 0, stream>>>(mask, bias);
  attn_main<<<NB * (SQ / 64), 256, 0, stream>>>(Q, Kb, Vt, bias, Out);
}

// Round 5
// 121.175 us; speedup vs baseline: 1.7774x; 1.1652x over previous
//
#include <hip/hip_runtime.h>
#include <hip/hip_bf16.h>

#define NB 16
#define SQ 2048
#define SK 2048
#define DH 64
#define RS 72          // LDS row stride in halfwords (144 B)
#define NKT (SK / 64)  // 32 key tiles of 64

#define KBLK 1024      // prepass blocks for K convert (1024*256*8 = 2M elems)
#define VBLK 512       // prepass blocks for V transpose (16*32 tiles)
#define BBLK 128       // prepass blocks for bias (128*256 = 32768)

typedef __attribute__((ext_vector_type(8))) short short8;
typedef __attribute__((ext_vector_type(8))) __bf16 bf16x8;
typedef __attribute__((ext_vector_type(4))) float floatx4;
typedef __attribute__((ext_vector_type(2))) unsigned uint2v;

__device__ __forceinline__ unsigned pk2(float a, float b) {
  __hip_bfloat162 h = __float22bfloat162_rn(make_float2(a, b));
  unsigned u; __builtin_memcpy(&u, &h, 4); return u;
}
__device__ __forceinline__ short bf1(float a) {
  __hip_bfloat16 h = __float2bfloat16(a);
  short s; __builtin_memcpy(&s, &h, 2); return s;
}
__device__ __forceinline__ floatx4 mfma16(short8 a, short8 b, floatx4 c) {
  return __builtin_amdgcn_mfma_f32_16x16x32_bf16(
      __builtin_bit_cast(bf16x8, a), __builtin_bit_cast(bf16x8, b), c, 0, 0, 0);
}

// ---------- fused prepass: K->bf16, V->bf16 transposed tile-packed, mask->bias ----------
__global__ __launch_bounds__(256)
void prepass(const float* __restrict__ K, const float* __restrict__ V,
             const int* __restrict__ m, short* __restrict__ Kb,
             short* __restrict__ Vt, float* __restrict__ bias) {
  __shared__ short tl[64 * RS];
  const int blk = blockIdx.x;
  const int t = threadIdx.x;
  if (blk < KBLK) {
    size_t i8 = ((size_t)blk * 256 + t) * 8;
    floatx4 a = *(const floatx4*)(K + i8);
    floatx4 b = *(const floatx4*)(K + i8 + 4);
    union { unsigned u[4]; short8 s; } w;
    w.u[0] = pk2(a[0], a[1]); w.u[1] = pk2(a[2], a[3]);
    w.u[2] = pk2(b[0], b[1]); w.u[3] = pk2(b[2], b[3]);
    *(short8*)(Kb + i8) = w.s;
  } else if (blk < KBLK + VBLK) {
    const int bt = blk - KBLK;            // b*32 + kt
    const int key = t >> 2, d0 = (t & 3) * 16;
    const float* src = V + ((size_t)bt * 64 + key) * 64 + d0;
#pragma unroll
    for (int c = 0; c < 4; ++c) {
      floatx4 v = *(const floatx4*)(src + 4 * c);
#pragma unroll
      for (int j = 0; j < 4; ++j) tl[(d0 + 4 * c + j) * RS + key] = bf1(v[j]);
    }
    __syncthreads();
    short* dst = Vt + (size_t)bt * 4096;
#pragma unroll
    for (int i = 0; i < 2; ++i) {
      int idx = i * 2048 + t * 8;          // flat [d][key]
      int row = idx >> 6, col = idx & 63;
      *(short8*)(dst + idx) = *(const short8*)(tl + row * RS + col);
    }
  } else {
    int i = (blk - KBLK - VBLK) * 256 + t;
    bias[i] = m[i] ? -1e30f : 0.0f;
  }
}

// ---------- main flash-attention kernel (transposed-S softmax) ----------
__global__ __launch_bounds__(256)
void attn_main(const float* __restrict__ Q, const short* __restrict__ Kb,
               const short* __restrict__ Vt, const float* __restrict__ bias,
               float* __restrict__ Out) {
  __shared__ __align__(16) short ks[64 * RS];      // K tile bf16 [64 keys][64 d + pad]
  __shared__ __align__(16) short vt[64 * RS];      // V^T tile bf16 [64 d][64 keys + pad]
  __shared__ __align__(16) short pb[4 * 16 * RS];  // per-wave P bf16 [16 q][64 k + pad]

  const int b    = blockIdx.x >> 5;
  const int qt   = blockIdx.x & 31;
  const int tid  = threadIdx.x;
  const int wave = tid >> 6;
  const int lane = tid & 63;
  const int L    = lane & 15;
  const int quad = lane >> 4;
  const int q0w  = qt * 64 + wave * 16;

  // ---- Q fragments (also the B-frag for S^T = K Q^T), scale*(log2 e) folded ----
  const float QS = 0.125f * 1.4426950408889634f;
  short8 qf[2];
  {
    const float* qp = Q + ((size_t)b * SQ + q0w + L) * DH + 8 * quad;
#pragma unroll
    for (int c = 0; c < 2; ++c) {
      floatx4 a  = *(const floatx4*)(qp + 32 * c);
      floatx4 a2 = *(const floatx4*)(qp + 32 * c + 4);
      union { unsigned u[4]; short8 s; } w;
      w.u[0] = pk2(a[0] * QS, a[1] * QS);
      w.u[1] = pk2(a[2] * QS, a[3] * QS);
      w.u[2] = pk2(a2[0] * QS, a2[1] * QS);
      w.u[3] = pk2(a2[2] * QS, a2[3] * QS);
      qf[c] = w.s;
    }
  }

  floatx4 o[4];
#pragma unroll
  for (int n = 0; n < 4; ++n) o[n] = (floatx4){0.f, 0.f, 0.f, 0.f};
  float m_q = -1e30f, l_q = 0.f;   // per-lane stats for query q0w+L

  short* pbw = pb + wave * 16 * RS;

  const short* kg = Kb + (size_t)b * SK * DH;
  const short* vg = Vt + (size_t)b * 32 * 4096;
  const float* bg = bias + b * SK;

  const int srow = tid >> 3;
  const int scol = (tid & 7) * 8;

  // prefetch tile 0
  short8 kr[2], vr[2];
#pragma unroll
  for (int i = 0; i < 2; ++i) {
    kr[i] = *(const short8*)(kg + i * 2048 + tid * 8);
    vr[i] = *(const short8*)(vg + i * 2048 + tid * 8);
  }

  for (int kt = 0; kt < NKT; ++kt) {
#pragma unroll
    for (int i = 0; i < 2; ++i) {
      int row = i * 32 + srow;
      *(short8*)(ks + row * RS + scol) = kr[i];
      *(short8*)(vt + row * RS + scol) = vr[i];
    }
    __syncthreads();

    if (kt + 1 < NKT) {
      const short* kn = kg + (size_t)(kt + 1) * 4096;
      const short* vn = vg + (size_t)(kt + 1) * 4096;
#pragma unroll
      for (int i = 0; i < 2; ++i) {
        kr[i] = *(const short8*)(kn + i * 2048 + tid * 8);
        vr[i] = *(const short8*)(vn + i * 2048 + tid * 8);
      }
    }

    // ---- S^T = K Q^T : s[t][r] = score(key kt*64+16t+4*quad+r, query q0w+L) ----
    floatx4 s[4];
#pragma unroll
    for (int t = 0; t < 4; ++t) {
      short8 kf0 = *(short8*)(ks + (16 * t + L) * RS + quad * 8);
      short8 kf1 = *(short8*)(ks + (16 * t + L) * RS + 32 + quad * 8);
      floatx4 z = (floatx4){0.f, 0.f, 0.f, 0.f};
      s[t] = mfma16(kf0, qf[0], z);
      s[t] = mfma16(kf1, qf[1], s[t]);
    }

    // ---- bias (per-key, aligned float4 per subtile) ----
    const float* bq = bg + kt * 64 + 4 * quad;
    float a[4][4];
    float rm = -1e30f;
#pragma unroll
    for (int t = 0; t < 4; ++t) {
      floatx4 bv = *(const floatx4*)(bq + 16 * t);
#pragma unroll
      for (int r = 0; r < 4; ++r) {
        a[t][r] = s[t][r] + bv[r];
        rm = fmaxf(rm, a[t][r]);
      }
    }
    // cross-quad reduction (2 shuffles instead of 4x4)
    rm = fmaxf(rm, __shfl_xor(rm, 16));
    rm = fmaxf(rm, __shfl_xor(rm, 32));
    float mn = fmaxf(m_q, rm);
    float alpha_q = __builtin_amdgcn_exp2f(m_q - mn);
    m_q = mn;

    float rs = 0.f;
#pragma unroll
    for (int t = 0; t < 4; ++t) {
      float p0 = __builtin_amdgcn_exp2f(a[t][0] - mn);
      float p1 = __builtin_amdgcn_exp2f(a[t][1] - mn);
      float p2 = __builtin_amdgcn_exp2f(a[t][2] - mn);
      float p3 = __builtin_amdgcn_exp2f(a[t][3] - mn);
      rs += (p0 + p1) + (p2 + p3);
      uint2v w; w.x = pk2(p0, p1); w.y = pk2(p2, p3);
      *(uint2v*)(pbw + L * RS + 16 * t + 4 * quad) = w;   // b64 write
    }
    rs += __shfl_xor(rs, 16);
    rs += __shfl_xor(rs, 32);
    l_q = alpha_q * l_q + rs;

    // ---- broadcast alpha into O's row layout (row = quad*4+r) ----
    float av[4];
#pragma unroll
    for (int r = 0; r < 4; ++r) av[r] = __shfl(alpha_q, quad * 4 + r);
#pragma unroll
    for (int n = 0; n < 4; ++n)
#pragma unroll
      for (int r = 0; r < 4; ++r) o[n][r] *= av[r];

    // ---- P fragments (A-layout, direct b128 reads) ----
    short8 pf0 = *(short8*)(pbw + L * RS + quad * 8);
    short8 pf1 = *(short8*)(pbw + L * RS + 32 + quad * 8);

    // ---- O += P V ----
#pragma unroll
    for (int n = 0; n < 4; ++n) {
      short8 vf0 = *(short8*)(vt + (16 * n + L) * RS + quad * 8);
      short8 vf1 = *(short8*)(vt + (16 * n + L) * RS + 32 + quad * 8);
      o[n] = mfma16(pf0, vf0, o[n]);
      o[n] = mfma16(pf1, vf1, o[n]);
    }
    __syncthreads();
  }

  // ---- epilogue: broadcast l, normalize, store ----
#pragma unroll
  for (int r = 0; r < 4; ++r) {
    float lv = __shfl(l_q, quad * 4 + r);
    float inv = 1.0f / lv;
    size_t row = (size_t)b * SQ + q0w + quad * 4 + r;
#pragma unroll
    for (int n = 0; n < 4; ++n)
      Out[row * DH + 16 * n + L] = o[n][r] * inv;
  }
}

extern "C" void kernel_launch(void* const* d_in, const int* in_sizes, int n_in,
                              void* d_out, int out_size, void* d_ws, size_t ws_size,
                              hipStream_t stream) {
  const float* Q = (const float*)d_in[0];
  const float* K = (const float*)d_in[1];
  const float* V = (const float*)d_in[2];
  const int* mask = (const int*)d_in[3];
  float* Out = (float*)d_out;

  short* Kb   = (short*)d_ws;
  short* Vt   = (short*)((char*)d_ws + (size_t)NB * SK * DH * 2);
  float* bias = (float*)((char*)d_ws + (size_t)NB * SK * DH * 4);

  prepass  <<<KBLK + VBLK + BBLK, 256, 0, stream>>>(K, V, mask, Kb, Vt, bias);
  attn_main<<<NB * (SQ / 64), 256, 0, stream>>>(Q, Kb, Vt, bias, Out);
}